// Round 25
// baseline (114.834 us; speedup 1.0000x reference)
//
#include <hip/hip_runtime.h>

#define NB 4
#define SEQ 4096
#define DIMK 1024
#define DKV 128
#define SCALE 0.08838834764831845f   // 1/sqrt(128)

typedef float  f32x4  __attribute__((ext_vector_type(4)));
typedef float  f32x16 __attribute__((ext_vector_type(16)));
typedef _Float16 f16x8 __attribute__((ext_vector_type(8)));

static __device__ __forceinline__ int pkrtz(float a, float b) {
    auto h = __builtin_amdgcn_cvt_pkrtz(a, b);   // __fp16 ext_vector(2)
    return __builtin_bit_cast(int, h);
}

// async global->LDS, 16B per lane; LDS dest = wave-uniform base + lane*16 (linear)
static __device__ __forceinline__ void gll16(const void* g, void* l) {
    __builtin_amdgcn_global_load_lds((const __attribute__((address_space(1))) char*)g,
                                     (__attribute__((address_space(3))) char*)l, 16, 0, 0);
}

// lane[i] <-> lane[i^32] exchange on the VALU (r24-proven: -4% attn, LDS-pipe relief).
static __device__ __forceinline__ float permswap_f(float v, int hi) {
    int x = __builtin_bit_cast(int, v);
    auto r = __builtin_amdgcn_permlane32_swap(x, x, false, false);
    int p = hi ? r[0] : r[1];
    return __builtin_bit_cast(float, p);
}
static __device__ __forceinline__ int permswap_i(int v, int hi) {
    auto r = __builtin_amdgcn_permlane32_swap(v, v, false, false);
    return hi ? r[0] : r[1];
}

// ---------------- kernel 0: transpose W -> f16 WT[3][128][1024] ----------------
__global__ void prep_wt(const float* __restrict__ Wq, const float* __restrict__ Wk,
                        const float* __restrict__ Wv, _Float16* __restrict__ WT) {
    int tid = blockIdx.x * 256 + threadIdx.x;
    int n  = tid & 127;
    int k  = (tid >> 7) & 1023;
    int w3 = tid >> 17;
    const float* W = (w3 == 0) ? Wq : (w3 == 1) ? Wk : Wv;
    WT[((size_t)w3 * 128 + n) * 1024 + k] = (_Float16)W[(size_t)k * 128 + n];
}

// ---------------- kernel 1: QKV projection + XCD sibling swizzle (r18/r20-proven) ----------------
__global__ __launch_bounds__(256, 2) void qkv_proj(
    const float* __restrict__ X,
    const float* __restrict__ bq, const float* __restrict__ bk, const float* __restrict__ bv,
    const _Float16* __restrict__ WT,
    _Float16* __restrict__ Qh, _Float16* __restrict__ Kh, _Float16* __restrict__ VTh) {

    __shared__ __attribute__((aligned(16))) char WTs[2][128 * 144];   // 36864 B
    const int t = threadIdx.x;
    const int w = t >> 6, l = t & 63;
    const int lrow = l & 15, lg = l >> 4;
    const int work = (blockIdx.x & 7) * 96 + (blockIdx.x >> 3);   // grid 768 = 8 x 96
    const int w3   = work % 3;
    const int tile = work / 3;
    const int r0 = tile * 64;

    f32x4 acc[8] = {};
    const float* xrow = X + (size_t)(r0 + w * 16 + lrow) * DIMK;
    const _Float16* Wbase = WT + (size_t)w3 * 128 * 1024;

    const int srow = t >> 3, spart = t & 7;        // + 32 rows per chunk index

    {
        int4 wreg[4];
        #pragma unroll
        for (int i = 0; i < 4; ++i)
            wreg[i] = *(const int4*)(Wbase + (size_t)(srow + 32 * i) * 1024 + spart * 8);
        #pragma unroll
        for (int i = 0; i < 4; ++i)
            *(int4*)(WTs[0] + (srow + 32 * i) * 144 + spart * 16) = wreg[i];
    }
    float4 xc0 = *(const float4*)(xrow + lg * 8);
    float4 xc1 = *(const float4*)(xrow + lg * 8 + 4);
    float4 xc2 = *(const float4*)(xrow + 32 + lg * 8);
    float4 xc3 = *(const float4*)(xrow + 32 + lg * 8 + 4);
    __syncthreads();

    for (int kt = 0; kt < 16; ++kt) {
        const int cur = kt & 1;
        const int k0n = ((kt + 1) & 15) * 64;      // wrap: last-iter data unused
        float4 xn0 = *(const float4*)(xrow + k0n + lg * 8);
        float4 xn1 = *(const float4*)(xrow + k0n + lg * 8 + 4);
        float4 xn2 = *(const float4*)(xrow + k0n + 32 + lg * 8);
        float4 xn3 = *(const float4*)(xrow + k0n + 32 + lg * 8 + 4);
        int4 wreg[4];
        #pragma unroll
        for (int i = 0; i < 4; ++i)
            wreg[i] = *(const int4*)(Wbase + (size_t)(srow + 32 * i) * 1024 + k0n + spart * 8);

        #pragma unroll
        for (int kk = 0; kk < 2; ++kk) {
            f16x8 a;
            float4 u = kk ? xc2 : xc0, v = kk ? xc3 : xc1;
            a[0] = (_Float16)u.x; a[1] = (_Float16)u.y; a[2] = (_Float16)u.z; a[3] = (_Float16)u.w;
            a[4] = (_Float16)v.x; a[5] = (_Float16)v.y; a[6] = (_Float16)v.z; a[7] = (_Float16)v.w;
            #pragma unroll
            for (int n = 0; n < 8; ++n) {
                f16x8 bf = *(const f16x8*)(WTs[cur] + (n * 16 + lrow) * 144 +
                                           kk * 64 + lg * 16);
                acc[n] = __builtin_amdgcn_mfma_f32_16x16x32_f16(a, bf, acc[n], 0, 0, 0);
            }
        }
        #pragma unroll
        for (int i = 0; i < 4; ++i)
            *(int4*)(WTs[cur ^ 1] + (srow + 32 * i) * 144 + spart * 16) = wreg[i];
        __syncthreads();
        xc0 = xn0; xc1 = xn1; xc2 = xn2; xc3 = xn3;
    }

    const float* bias = (w3 == 0) ? bq : (w3 == 1) ? bk : bv;
    #pragma unroll
    for (int n = 0; n < 8; ++n) {
        int col = n * 16 + lrow;
        float bv_ = bias[col];
        #pragma unroll
        for (int j = 0; j < 4; ++j) {
            int grow = r0 + w * 16 + lg * 4 + j;
            float val = acc[n][j] + bv_;
            if (w3 == 0) {
                Qh[(size_t)grow * DKV + col] = (_Float16)(val * SCALE);
            } else if (w3 == 1) {
                Kh[(size_t)grow * DKV + col] = (_Float16)val;
            } else {
                int b = grow >> 12, sp = grow & 4095;
                VTh[((size_t)b * DKV + col) * SEQ + sp] = (_Float16)val;
            }
        }
    }
}

// ---------------- kernel 2: flash attention (r24 + unpinned vmcnt waits) ----------------
// Single delta vs the verified r24 (74.4us): remove the two sched_barrier(0)s after
// the vmcnt(8) waits. Rule-18's hazard is register-only MFMA hoisted past an
// inline-asm wait; here the MFMAs consume ds_read results (memory ops, ordered by
// the "memory" clobber), so the fence was redundant scheduler pinning. The fences
// guarding gll buffer-overwrite (after lgkmcnt(0), before STAGE_*) remain.
__global__ __launch_bounds__(256, 2) void attn_kernel(
    const _Float16* __restrict__ Qh, const _Float16* __restrict__ Kh,
    const _Float16* __restrict__ VTh, float* __restrict__ out) {

    __shared__ __attribute__((aligned(16))) char lds[65536];

    const int t = threadIdx.x;
    const int w = t >> 6, l = t & 63;
    const int lq = l & 31;          // q column within tile
    const int hi = l >> 5;

    // XCD-chunked swizzle over 512 blocks
    const int work = (blockIdx.x & 7) * 64 + (blockIdx.x >> 3);
    const int b  = work >> 7;            // 128 q-tiles per batch
    const int qt = work & 127;
    const int q0 = qt * 32;

    char* Kw = lds + w * 16384;          // [32 k][128 dk] f16: LDS[r][x]=K[r][x^(r&15)]
    char* Vw = Kw + 8192;                // [128 dv][32 k] f16: chunk-XOR (dv>>1)&3

    f16x8 qf[8];
    #pragma unroll
    for (int c = 0; c < 8; ++c)
        qf[c] = *(const f16x8*)(Qh + (size_t)(b * SEQ + q0 + lq) * DKV + c * 16 + hi * 8);

    f32x16 o[4] = {};                    // O^T: 4 dv-tiles of 32, q = lq
    float m = -INFINITY, lsum = 0.f;

    const _Float16* Kbase = Kh + (size_t)(b * SEQ + w * 1024) * DKV;
    const _Float16* Vbase = VTh + (size_t)b * DKV * SEQ + w * 1024;

    const int krow_ = l >> 4;                       // + 4 per K-chunk
    const int vdv_  = l >> 2;                       // + 16 per V-chunk

#define STAGE_K(KOFF) {                                                                   \
        _Pragma("unroll")                                                                 \
        for (int i = 0; i < 8; ++i) {                                                     \
            int row = 4 * i + krow_;                                                      \
            int part = (l & 15) ^ (row & 15);                                             \
            gll16(Kbase + (size_t)((KOFF) + row) * DKV + part * 8, Kw + i * 1024);        \
        }                                                                                 \
    }
#define STAGE_V(KOFF) {                                                                   \
        _Pragma("unroll")                                                                 \
        for (int i = 0; i < 8; ++i) {                                                     \
            int dv = 16 * i + vdv_;                                                       \
            int p = (l & 3) ^ ((dv >> 1) & 3);                                            \
            gll16(Vbase + (size_t)dv * SEQ + (KOFF) + p * 8, Vw + i * 1024);              \
        }                                                                                 \
    }

    // ---- prologue: stage tile 0 (8 K-glls then 8 V-glls outstanding) ----
    STAGE_K(0)
    STAGE_V(0)

    for (int kt = 0; kt < 32; ++kt) {
        const int kn = ((kt + 1) & 31) * 32;       // next tile offset (wrap: unused data)

        // wait K(t) only — the 8 oldest; V(t) still in flight (T4 counted vmcnt)
        asm volatile("s_waitcnt vmcnt(8)" ::: "memory");

        // ---- S^T = K Q^T : two independent 4-deep MFMA chains ----
        f32x16 sa = {}, sb = {};
        __builtin_amdgcn_s_setprio(1);
        #pragma unroll
        for (int c = 0; c < 4; ++c) {
            f16x8 kfa = *(const f16x8*)(Kw + lq * 256 +
                                        (((2 * c + hi) * 16) ^ ((lq & 15) << 4)));
            f16x8 kfb = *(const f16x8*)(Kw + lq * 256 +
                                        (((2 * (c + 4) + hi) * 16) ^ ((lq & 15) << 4)));
            sa = __builtin_amdgcn_mfma_f32_32x32x16_f16(kfa, qf[c], sa, 0, 0, 0);
            sb = __builtin_amdgcn_mfma_f32_32x32x16_f16(kfb, qf[c + 4], sb, 0, 0, 0);
        }
        __builtin_amdgcn_s_setprio(0);
        f32x16 s = sa + sb;

        // K ds_reads retired -> safe to overwrite K region with next tile
        asm volatile("s_waitcnt lgkmcnt(0)" ::: "memory");
        __builtin_amdgcn_sched_barrier(0);
        STAGE_K(kn)

        // ---- in-register online softmax (tree reductions; VALU exchanges) ----
        float red[8];
        #pragma unroll
        for (int r = 0; r < 8; ++r) red[r] = fmaxf(s[2 * r], s[2 * r + 1]);
        #pragma unroll
        for (int r = 0; r < 4; ++r) red[r] = fmaxf(red[r], red[r + 4]);
        red[0] = fmaxf(red[0], red[2]);
        red[1] = fmaxf(red[1], red[3]);
        float tm = fmaxf(red[0], red[1]);
        tm = fmaxf(tm, permswap_f(tm, hi));

        if (__any(tm > m + 8.f)) {           // defer-max (T13)
            float mnew = fmaxf(m, tm);
            float corr = __expf(m - mnew);
            m = mnew;
            lsum *= corr;
            #pragma unroll
            for (int dvt = 0; dvt < 4; ++dvt) o[dvt] *= corr;
        }
        #pragma unroll
        for (int r = 0; r < 16; ++r) s[r] = __expf(s[r] - m);
        float sr[8];
        #pragma unroll
        for (int r = 0; r < 8; ++r) sr[r] = s[2 * r] + s[2 * r + 1];
        #pragma unroll
        for (int r = 0; r < 4; ++r) sr[r] += sr[r + 4];
        sr[0] += sr[2]; sr[1] += sr[3];
        float ts = sr[0] + sr[1];
        ts += permswap_f(ts, hi);
        lsum += ts;

        // pack P to f16 (T12)
        int wv[8];
        #pragma unroll
        for (int i = 0; i < 8; ++i) wv[i] = pkrtz(s[2 * i], s[2 * i + 1]);

        // wait V(t) only — the 8 oldest now; K(t+1) still in flight
        asm volatile("s_waitcnt vmcnt(8)" ::: "memory");

        // ---- O^T += V^T P : 2 k-slices x 4 dv-tiles (V from LDS) ----
        #pragma unroll
        for (int s_ = 0; s_ < 2; ++s_) {
            const int base = s_ * 4;
            int x0 = permswap_i(wv[base + 0], hi);
            int x1 = permswap_i(wv[base + 1], hi);
            int x2 = permswap_i(wv[base + 2], hi);
            int x3 = permswap_i(wv[base + 3], hi);
            union { int i[4]; f16x8 v; } bu;
            bu.i[0] = hi ? x2 : wv[base + 0];
            bu.i[1] = hi ? x3 : wv[base + 1];
            bu.i[2] = hi ? wv[base + 2] : x0;
            bu.i[3] = hi ? wv[base + 3] : x1;
            __builtin_amdgcn_s_setprio(1);
            #pragma unroll
            for (int dvt = 0; dvt < 4; ++dvt) {
                int rv = dvt * 32 + lq;
                f16x8 vf = *(const f16x8*)(Vw + rv * 64 +
                                           (((s_ * 2 + hi) ^ ((rv >> 1) & 3)) * 16));
                o[dvt] = __builtin_amdgcn_mfma_f32_32x32x16_f16(vf, bu.v, o[dvt], 0, 0, 0);
            }
            __builtin_amdgcn_s_setprio(0);
        }

        // V ds_reads retired -> stage next V tile
        asm volatile("s_waitcnt lgkmcnt(0)" ::: "memory");
        __builtin_amdgcn_sched_barrier(0);
        STAGE_V(kn)
    }
#undef STAGE_K
#undef STAGE_V
    asm volatile("s_waitcnt vmcnt(0)" ::: "memory");   // drain stray glls before LDS reuse

    // -------- 2-round tree merge of 4 wave partials (same 32 q-cols) --------
    float* obuf  = (float*)lds;                 // 2 snapshots x 4096 f32 = 32 KB
    float* mlbuf = (float*)(lds + 49152);       // 2 snapshots x 64 f32

    __syncthreads();
    if (w == 1 || w == 3) {
        int sb_ = (w == 3);
        #pragma unroll
        for (int dvt = 0; dvt < 4; ++dvt)
            #pragma unroll
            for (int r = 0; r < 16; ++r)
                obuf[sb_ * 4096 + (dvt * 16 + r) * 64 + l] = o[dvt][r];
        if (l < 32) {
            mlbuf[sb_ * 64 + l * 2 + 0] = m;
            mlbuf[sb_ * 64 + l * 2 + 1] = lsum;
        }
    }
    __syncthreads();
    if (w == 0 || w == 2) {
        int sb_ = (w == 2);
        float mo  = mlbuf[sb_ * 64 + lq * 2 + 0];
        float lo_ = mlbuf[sb_ * 64 + lq * 2 + 1];
        float mn = fmaxf(m, mo);
        float ca = __expf(m - mn);
        float cb = __expf(mo - mn);
        m = mn;
        lsum = lsum * ca + lo_ * cb;
        #pragma unroll
        for (int dvt = 0; dvt < 4; ++dvt)
            #pragma unroll
            for (int r = 0; r < 16; ++r)
                o[dvt][r] = o[dvt][r] * ca + obuf[sb_ * 4096 + (dvt * 16 + r) * 64 + l] * cb;
    }
    __syncthreads();
    if (w == 2) {
        #pragma unroll
        for (int dvt = 0; dvt < 4; ++dvt)
            #pragma unroll
            for (int r = 0; r < 16; ++r)
                obuf[(dvt * 16 + r) * 64 + l] = o[dvt][r];
        if (l < 32) {
            mlbuf[l * 2 + 0] = m;
            mlbuf[l * 2 + 1] = lsum;
        }
    }
    __syncthreads();
    if (w == 0) {
        float mo  = mlbuf[lq * 2 + 0];
        float lo_ = mlbuf[lq * 2 + 1];
        float mn = fmaxf(m, mo);
        float ca = __expf(m - mn);
        float cb = __expf(mo - mn);
        float rl = 1.0f / (lsum * ca + lo_ * cb);
        #pragma unroll
        for (int dvt = 0; dvt < 4; ++dvt)
            #pragma unroll
            for (int r = 0; r < 16; ++r)
                o[dvt][r] = (o[dvt][r] * ca + obuf[(dvt * 16 + r) * 64 + l] * cb) * rl;
    }
    __syncthreads();
    // -------- transpose O^T -> row-major via LDS, coalesced store --------
    float* tbuf = (float*)lds;                  // [32][132] f32
    if (w == 0) {
        #pragma unroll
        for (int dvt = 0; dvt < 4; ++dvt)
            #pragma unroll
            for (int r = 0; r < 16; ++r) {
                int dv = dvt * 32 + (r & 3) + 8 * (r >> 2) + 4 * hi;
                tbuf[lq * 132 + dv] = o[dvt][r];
            }
    }
    __syncthreads();
    const size_t obase = (size_t)(b * SEQ + qt * 32) * DKV;
    int row = t >> 3, c0 = (t & 7) * 16;
    #pragma unroll
    for (int i = 0; i < 4; ++i) {
        float4 v = *(const float4*)(tbuf + row * 132 + c0 + i * 4);
        *(float4*)(out + obase + row * 128 + c0 + i * 4) = v;
    }
}

extern "C" void kernel_launch(void* const* d_in, const int* in_sizes, int n_in,
                              void* d_out, int out_size, void* d_ws, size_t ws_size,
                              hipStream_t stream) {
    const float* X  = (const float*)d_in[0];
    const float* Wq = (const float*)d_in[1];
    const float* bq = (const float*)d_in[2];
    const float* Wk = (const float*)d_in[3];
    const float* bk = (const float*)d_in[4];
    const float* Wv = (const float*)d_in[5];
    const float* bv = (const float*)d_in[6];
    float* out = (float*)d_out;

    const size_t nqe = (size_t)NB * SEQ * DKV;            // 2M elements
    _Float16* Qh  = (_Float16*)d_ws;
    _Float16* Kh  = Qh  + nqe;
    _Float16* VTh = Kh  + nqe;
    _Float16* WTh = VTh + nqe;                            // 3*128*1024 f16

    prep_wt<<<(3 * 1024 * 128) / 256, 256, 0, stream>>>(Wq, Wk, Wv, WTh);
    qkv_proj<<<(NB * SEQ / 64) * 3, 256, 0, stream>>>(X, bq, bk, bv, WTh, Qh, Kh, VTh);
    attn_kernel<<<NB * 128, 256, 0, stream>>>(Qh, Kh, VTh, out);
}